// Round 8
// baseline (1860.434 us; speedup 1.0000x reference)
//
#include <hip/hip_runtime.h>

typedef unsigned short u16;
typedef __attribute__((ext_vector_type(8))) short s8v;
typedef __attribute__((ext_vector_type(4))) float f4v;
typedef __attribute__((ext_vector_type(4))) unsigned short us4v;
typedef __attribute__((ext_vector_type(8))) unsigned short us8v;

#define D_ 1024
#define B_ 2
#define T_ 2048
#define F_ 2048
#define CHUNK 512
#define NCHUNK 4
#define EPS_ 1e-6f
#define RSCALE 0.044194173824159216f   // sqrt(2/1024)

__device__ __forceinline__ u16 bf16h(float a) {
    unsigned u = __float_as_uint(a);
    return (u16)((u + 0x7fffu + ((u >> 16) & 1u)) >> 16);
}
__device__ __forceinline__ float bf2f(u16 h) {
    return __uint_as_float(((unsigned)h) << 16);
}
__device__ __forceinline__ void bsplit2(float a, u16& h, u16& l) {
    h = bf16h(a);
    l = bf16h(a - bf2f(h));
}

#define GLOAD16(gp, lp) __builtin_amdgcn_global_load_lds( \
    (const __attribute__((address_space(1))) unsigned int*)(gp), \
    (__attribute__((address_space(3))) unsigned int*)(lp), 16, 0, 0)

// ===========================================================================
// R1-verbatim fp32 kernels (den-determining chain — DO NOT perturb: their
// output bits reproduce the round-1 pipeline that passed at absmax 96).
// ===========================================================================
template<int EPI>
__global__ __launch_bounds__(256)
void sgemm128(const float* __restrict__ A, const float* __restrict__ B,
              float* __restrict__ C, int M, int N, int K, int ldc) {
    __shared__ float As[16][132];
    __shared__ float Bs[16][132];
    const int tid = threadIdx.x;
    const int bm = blockIdx.x * 128;
    const int bn = blockIdx.y * 128;
    const int tx = tid & 15, ty = tid >> 4;
    float acc[2][2][4][4] = {};
    const float* Ab = A + (size_t)bm * K;
    const float* Bb = B + bn;

    for (int k0 = 0; k0 < K; k0 += 16) {
#pragma unroll
        for (int l = 0; l < 2; ++l) {
            int idx = tid + l * 256;
            int r  = idx >> 2;
            int c4 = (idx & 3) << 2;
            float4 a = *(const float4*)(Ab + (size_t)r * K + k0 + c4);
            As[c4 + 0][r] = a.x; As[c4 + 1][r] = a.y;
            As[c4 + 2][r] = a.z; As[c4 + 3][r] = a.w;
            int rb = idx >> 5;
            int cb = (idx & 31) << 2;
            *(float4*)(&Bs[rb][cb]) = *(const float4*)(Bb + (size_t)(k0 + rb) * N + cb);
        }
        __syncthreads();
#pragma unroll
        for (int k = 0; k < 16; ++k) {
            float4 a0 = *(float4*)(&As[k][ty * 4]);
            float4 a1 = *(float4*)(&As[k][64 + ty * 4]);
            float4 b0 = *(float4*)(&Bs[k][tx * 4]);
            float4 b1 = *(float4*)(&Bs[k][64 + tx * 4]);
            float av[2][4] = {{a0.x, a0.y, a0.z, a0.w}, {a1.x, a1.y, a1.z, a1.w}};
            float bv[2][4] = {{b0.x, b0.y, b0.z, b0.w}, {b1.x, b1.y, b1.z, b1.w}};
#pragma unroll
            for (int ri = 0; ri < 2; ++ri)
#pragma unroll
                for (int i = 0; i < 4; ++i)
#pragma unroll
                    for (int ci = 0; ci < 2; ++ci)
#pragma unroll
                        for (int j = 0; j < 4; ++j)
                            acc[ri][ci][i][j] = fmaf(av[ri][i], bv[ci][j], acc[ri][ci][i][j]);
        }
        __syncthreads();
    }

#pragma unroll
    for (int ri = 0; ri < 2; ++ri)
#pragma unroll
        for (int i = 0; i < 4; ++i) {
            int R = bm + ri * 64 + ty * 4 + i;
#pragma unroll
            for (int ci = 0; ci < 2; ++ci) {
                int col = bn + ci * 64 + tx * 4;
                if (EPI == 0) {
                    float4 v = make_float4(acc[ri][ci][i][0], acc[ri][ci][i][1],
                                           acc[ri][ci][i][2], acc[ri][ci][i][3]);
                    *(float4*)(&C[(size_t)R * ldc + col]) = v;
                } else {
                    float cs[4], sn[4];
#pragma unroll
                    for (int j = 0; j < 4; ++j)
                        __sincosf(acc[ri][ci][i][j], &sn[j], &cs[j]);
                    float4 cv = make_float4(RSCALE * cs[0], RSCALE * cs[1],
                                            RSCALE * cs[2], RSCALE * cs[3]);
                    float4 sv = make_float4(RSCALE * sn[0], RSCALE * sn[1],
                                            RSCALE * sn[2], RSCALE * sn[3]);
                    *(float4*)(&C[(size_t)R * ldc + col])      = cv;
                    *(float4*)(&C[(size_t)R * ldc + col + D_]) = sv;
                }
            }
        }
}

__global__ __launch_bounds__(256)
void pall_kernel(const float* __restrict__ Qp, const float* __restrict__ Kp,
                 float* __restrict__ P) {
    const int tt = blockIdx.x >> 4, ts = blockIdx.x & 15;
    const int c = blockIdx.y, b = blockIdx.z;
    const int t0 = tt * 32, s0 = ts * 32;
    float* Pc = P + (((size_t)b * NCHUNK + c) * CHUNK) * CHUNK;
    const int tid = threadIdx.x;
    if (tt < ts) {
        int r = tid >> 3, c4 = (tid & 7) << 2;
        *(float4*)(&Pc[(size_t)(t0 + r) * CHUNK + s0 + c4]) = make_float4(0, 0, 0, 0);
        return;
    }
    __shared__ float Qs[32][36];
    __shared__ float Ks[32][36];
    const int tx = tid & 15, ty = tid >> 4;
    float acc[2][2] = {};
    const float* Qb = Qp + ((size_t)b * T_ + c * CHUNK + t0) * F_;
    const float* Kb = Kp + ((size_t)b * T_ + c * CHUNK + s0) * F_;
    for (int f0 = 0; f0 < F_; f0 += 32) {
        int r = tid >> 3, c4 = (tid & 7) << 2;
        *(float4*)(&Qs[r][c4]) = *(const float4*)(Qb + (size_t)r * F_ + f0 + c4);
        *(float4*)(&Ks[r][c4]) = *(const float4*)(Kb + (size_t)r * F_ + f0 + c4);
        __syncthreads();
#pragma unroll
        for (int k = 0; k < 32; ++k) {
            float q0 = Qs[ty * 2][k],     q1 = Qs[ty * 2 + 1][k];
            float k0v = Ks[tx * 2][k],    k1v = Ks[tx * 2 + 1][k];
            acc[0][0] = fmaf(q0, k0v, acc[0][0]);
            acc[0][1] = fmaf(q0, k1v, acc[0][1]);
            acc[1][0] = fmaf(q1, k0v, acc[1][0]);
            acc[1][1] = fmaf(q1, k1v, acc[1][1]);
        }
        __syncthreads();
    }
#pragma unroll
    for (int i = 0; i < 2; ++i)
#pragma unroll
        for (int j = 0; j < 2; ++j) {
            int t = t0 + ty * 2 + i, s = s0 + tx * 2 + j;
            Pc[(size_t)t * CHUNK + s] = (s <= t) ? acc[i][j] : 0.0f;
        }
}

__global__ __launch_bounds__(256)
void csum_kernel(const float* __restrict__ Kp, float* __restrict__ Zpre) {
    const int f = blockIdx.x * 256 + threadIdx.x;
    const int c = blockIdx.y, b = blockIdx.z;
    const float* base = Kp + ((size_t)b * T_ + c * CHUNK) * F_ + f;
    float acc = 0.f;
    for (int s = 0; s < CHUNK; ++s) acc += base[(size_t)s * F_];
    Zpre[((size_t)b * NCHUNK + c) * F_ + f] = acc;
}

__global__ __launch_bounds__(256)
void zprefix_kernel(float* __restrict__ Zpre) {
    const int f = blockIdx.x * 256 + threadIdx.x;
    const int b = blockIdx.y;
    float run = 0.f;
    for (int c = 0; c < NCHUNK; ++c) {
        size_t idx = ((size_t)b * NCHUNK + c) * F_ + f;
        float v = Zpre[idx];
        Zpre[idx] = run;
        run += v;
    }
}

__global__ __launch_bounds__(256)
void den_kernel(const float* __restrict__ Qp, const float* __restrict__ Zpre,
                const float* __restrict__ P, float* __restrict__ den) {
    const int b = blockIdx.y;
    const int w = threadIdx.x >> 6, lane = threadIdx.x & 63;
    const int t = blockIdx.x * 4 + w;
    const int c = t / CHUNK, tin = t % CHUNK;
    const float* q = Qp + ((size_t)b * T_ + t) * F_;
    const float* z = Zpre + ((size_t)b * NCHUNK + c) * F_;
    float acc = 0.f;
    for (int f = lane; f < F_; f += 64) acc = fmaf(q[f], z[f], acc);
    const float* prow = P + (((size_t)b * NCHUNK + c) * CHUNK + tin) * CHUNK;
    for (int s = lane; s < CHUNK; s += 64) acc += prow[s];
#pragma unroll
    for (int off = 32; off; off >>= 1) acc += __shfl_down(acc, off);
    if (lane == 0) den[(size_t)b * T_ + t] = acc;
}

// ===========================================================================
// Pair-split bf16 MFMA GEMM (numerator path only — error budget ~2^-17 rel,
// amplification-safe per analysis). C = A @ B^T, A:[M,K], B:[N,K], 2 planes.
// NT=3 terms (hh, hl, lh). Tile 128x128, BK=32, 4 waves.
// EPI: 0 = fp32 store (ldo); 3 = causal mask (col<=row), pair store (ldo),
//      fully-masked tiles zero-filled; 5 = pair store of acc/(den[row]+eps),
//      K-loop truncated to bm+128 (P zero above diagonal).
// ===========================================================================
template<int EPI>
__global__ __launch_bounds__(256)
void mgemm2(const u16* __restrict__ A0, const u16* __restrict__ A1,
            const u16* __restrict__ B0, const u16* __restrict__ B1,
            int K, float* __restrict__ Cf, u16* __restrict__ O0,
            u16* __restrict__ O1, const float* __restrict__ dptr, int ldo) {
    __shared__ u16 lds[4 * 4096];              // 32 KB: Ah Al Bh Bl
    const int tid = threadIdx.x;
    const int bm = blockIdx.x * 128, bn = blockIdx.y * 128;

    if (EPI == 3 && bm + 128 <= bn) {          // fully-masked tile: zero-fill
        us8v zz = {0, 0, 0, 0, 0, 0, 0, 0};
#pragma unroll
        for (int i = 0; i < 8; ++i) {
            int j = i * 256 + tid;
            int r = j >> 4, c8 = (j & 15) * 8;
            size_t o = (size_t)(bm + r) * ldo + bn + c8;
            *(us8v*)&O0[o] = zz;
            *(us8v*)&O1[o] = zz;
        }
        return;
    }

    const int kend = (EPI == 5) ? (bm + 128 < K ? bm + 128 : K) : K;

    const int wv = tid >> 6, lane = tid & 63;
    const int wr = (wv >> 1) * 64, wc = (wv & 1) * 64;
    const int lr = lane & 15, kb = lane >> 4;

    f4v acc[4][4] = {};

    const int sr0 = tid >> 2, sc0 = (tid & 3) * 8;
    const int sl0 = tid * 8, sl1 = (tid + 256) * 8;

    for (int k0 = 0; k0 < kend; k0 += 32) {
        size_t ga0 = (size_t)(bm + sr0) * K + k0 + sc0;
        size_t ga1 = ga0 + (size_t)64 * K;
        size_t gb0 = (size_t)(bn + sr0) * K + k0 + sc0;
        size_t gb1 = gb0 + (size_t)64 * K;
        GLOAD16(A0 + ga0, lds + 0 * 4096 + sl0);
        GLOAD16(A0 + ga1, lds + 0 * 4096 + sl1);
        GLOAD16(A1 + ga0, lds + 1 * 4096 + sl0);
        GLOAD16(A1 + ga1, lds + 1 * 4096 + sl1);
        GLOAD16(B0 + gb0, lds + 2 * 4096 + sl0);
        GLOAD16(B0 + gb1, lds + 2 * 4096 + sl1);
        GLOAD16(B1 + gb0, lds + 3 * 4096 + sl0);
        GLOAD16(B1 + gb1, lds + 3 * 4096 + sl1);
        __syncthreads();

        constexpr int TA[3] = {0, 0, 1};
        constexpr int TB[3] = {0, 1, 0};
#pragma unroll
        for (int t = 0; t < 3; ++t) {
            const u16* la = lds + TA[t] * 4096;
            const u16* lb = lds + (2 + TB[t]) * 4096;
            s8v af[4], bfr[4];
#pragma unroll
            for (int i = 0; i < 4; ++i) {
                af[i]  = *(const s8v*)&la[(wr + i * 16 + lr) * 32 + kb * 8];
                bfr[i] = *(const s8v*)&lb[(wc + i * 16 + lr) * 32 + kb * 8];
            }
#pragma unroll
            for (int i = 0; i < 4; ++i)
#pragma unroll
                for (int j = 0; j < 4; ++j)
                    acc[i][j] = __builtin_amdgcn_mfma_f32_16x16x32_bf16(
                        af[i], bfr[j], acc[i][j], 0, 0, 0);
        }
        __syncthreads();
    }

    // C/D layout (gfx950): col = lane&15, row = (lane>>4)*4 + reg.
    const int rbase = bm + wr + kb * 4;
    const int cbase = bn + wc + lr;
#pragma unroll
    for (int i = 0; i < 4; ++i) {
        const int R0 = rbase + i * 16;
#pragma unroll
        for (int j = 0; j < 4; ++j) {
            const int Cc = cbase + j * 16;
            f4v v = acc[i][j];
            if (EPI == 0) {
#pragma unroll
                for (int q = 0; q < 4; ++q)
                    Cf[(size_t)(R0 + q) * ldo + Cc] = v[q];
            } else if (EPI == 3) {
#pragma unroll
                for (int q = 0; q < 4; ++q) {
                    int t = R0 + q;
                    float val = (Cc <= t) ? v[q] : 0.0f;
                    u16 h, l; bsplit2(val, h, l);
                    size_t o = (size_t)t * ldo + Cc;
                    O0[o] = h; O1[o] = l;
                }
            } else if (EPI == 5) {
#pragma unroll
                for (int q = 0; q < 4; ++q) {
                    float g = v[q] / (dptr[R0 + q] + EPS_);
                    u16 h, l; bsplit2(g, h, l);
                    size_t o = (size_t)(R0 + q) * ldo + Cc;
                    O0[o] = h; O1[o] = l;
                }
            }
        }
    }
}

// fp32 -> 2 bf16 planes, flat. n4 = elems/4.
__global__ __launch_bounds__(256)
void convk2(const float* __restrict__ in, u16* __restrict__ o0,
            u16* __restrict__ o1, int n4) {
    int i = blockIdx.x * 256 + threadIdx.x;
    if (i >= n4) return;
    float4 v = ((const float4*)in)[i];
    us4v p0, p1;
    float vv[4] = {v.x, v.y, v.z, v.w};
#pragma unroll
    for (int q = 0; q < 4; ++q) {
        u16 h, l; bsplit2(vv[q], h, l);
        p0[q] = h; p1[q] = l;
    }
    ((us4v*)o0)[i] = p0;
    ((us4v*)o1)[i] = p1;
}

// [R x inW] fp32 -> transposed pair planes [inW x R] (out row stride outW=R).
// grid (inW/32, R/32).
__global__ __launch_bounds__(256)
void tpc(const float* __restrict__ in, u16* __restrict__ oh,
         u16* __restrict__ ol, int inW, int outW) {
    __shared__ float t[32][33];
    const int r = threadIdx.x >> 3, c4 = (threadIdx.x & 7) << 2;
    const int row0 = blockIdx.y * 32, col0 = blockIdx.x * 32;
    float4 v = *(const float4*)&in[(size_t)(row0 + r) * inW + col0 + c4];
    t[r][c4 + 0] = v.x; t[r][c4 + 1] = v.y;
    t[r][c4 + 2] = v.z; t[r][c4 + 3] = v.w;
    __syncthreads();
    us4v h4, l4;
#pragma unroll
    for (int i = 0; i < 4; ++i) {
        u16 h, l; bsplit2(t[c4 + i][r], h, l);
        h4[i] = h; l4[i] = l;
    }
    size_t o = (size_t)(col0 + r) * outW + row0 + c4;
    *(us4v*)&oh[o] = h4;
    *(us4v*)&ol[o] = l4;
}

// ---------------------------------------------------------------------------
extern "C" void kernel_launch(void* const* d_in, const int* in_sizes, int n_in,
                              void* d_out, int out_size, void* d_ws, size_t ws_size,
                              hipStream_t stream) {
    const float* x     = (const float*)d_in[0];
    const float* Wq    = (const float*)d_in[1];
    const float* Wk    = (const float*)d_in[2];
    const float* Wv    = (const float*)d_in[3];
    const float* Wo    = (const float*)d_in[4];
    const float* omega = (const float*)d_in[5];
    float* out = (float*)d_out;

    char* WS = (char*)d_ws;
    // byte-offset layout; peak 121 MB (124 MB proven usable in round 3)
    float* Wqo = (float*)(WS + 0);                 // 4 MB
    float* Wko = (float*)(WS + 4194304);           // 4 MB
    u16*  WoTh = (u16*)(WS + 8388608);             // 2 MB
    u16*  WoTl = (u16*)(WS + 10485760);            // 2 MB
    float* den = (float*)(WS + 12582912);          // 16 KB (fp32[4096])
    float* Zpre = (float*)(WS + 12599296);         // 32 KB (per-batch [4][2048])
    float* Qf  = (float*)(WS + 13631488);          // 16 MB  (batch phi fp32)
    float* Kf  = (float*)(WS + 30408704);          // 16 MB
    float* Vf  = (float*)(WS + 47185920);          // 8 MB   (batch V fp32)
    float* Pd  = (float*)(WS + 55574528);          // 4 MB   (diag-chunk P fp32)
    u16* Qph = (u16*)(WS + 59768832);              // 8 MB each plane
    u16* Qpl = (u16*)(WS + 68157440);
    u16* Kph = (u16*)(WS + 76546048);
    u16* Kpl = (u16*)(WS + 84934656);
    u16* VTh = (u16*)(WS + 93323264);              // 4 MB each
    u16* VTl = (u16*)(WS + 97517568);
    u16* P2h = (u16*)(WS + 101711872);             // 8 MB each
    u16* P2l = (u16*)(WS + 110100480);
    u16* g2h = (u16*)(WS + 118489088);             // 4 MB each
    u16* g2l = (u16*)(WS + 122683392);             // ends 126,877,696

    // folded projection weights (R1-exact): Wqo = Wq@omega, Wko = Wk@omega
    sgemm128<0><<<dim3(8, 8), 256, 0, stream>>>(Wq, omega, Wqo, D_, D_, D_, D_);
    sgemm128<0><<<dim3(8, 8), 256, 0, stream>>>(Wk, omega, Wko, D_, D_, D_, D_);
    // WoT pair planes (num path)
    tpc<<<dim3(32, 32), 256, 0, stream>>>(Wo, WoTh, WoTl, 1024, 1024);

    for (int b = 0; b < 2; ++b) {
        const float* xb = x + (size_t)b * T_ * D_;
        // --- den-determining chain: R1-exact kernels, per-batch launches ---
        sgemm128<1><<<dim3(16, 8), 256, 0, stream>>>(xb, Wqo, Qf, T_, D_, D_, F_);
        sgemm128<1><<<dim3(16, 8), 256, 0, stream>>>(xb, Wko, Kf, T_, D_, D_, F_);
        sgemm128<0><<<dim3(16, 8), 256, 0, stream>>>(xb, Wv, Vf, T_, D_, D_, D_);
        csum_kernel<<<dim3(8, 4, 1), 256, 0, stream>>>(Kf, Zpre);
        zprefix_kernel<<<dim3(8, 1), 256, 0, stream>>>(Zpre);
        pall_kernel<<<dim3(256, 4, 1), 256, 0, stream>>>(Qf, Kf, Pd);
        den_kernel<<<dim3(512, 1), 256, 0, stream>>>(Qf, Zpre, Pd, den + b * T_);

        // --- numerator path: pair-split bf16 MFMA ---
        convk2<<<4096, 256, 0, stream>>>(Qf, Qph, Qpl, 1048576);
        convk2<<<4096, 256, 0, stream>>>(Kf, Kph, Kpl, 1048576);
        tpc<<<dim3(32, 64), 256, 0, stream>>>(Vf, VTh, VTl, 1024, 2048);

        // P = causal-masked Qphi @ Kphi^T (pair store)
        mgemm2<3><<<dim3(16, 16), 256, 0, stream>>>(
            Qph, Qpl, Kph, Kpl, 2048, nullptr, P2h, P2l, nullptr, 2048);
        // gamma = (P @ V) / (den + eps)
        mgemm2<5><<<dim3(16, 8), 256, 0, stream>>>(
            P2h, P2l, VTh, VTl, 2048, nullptr, g2h, g2l, den + b * T_, 1024);
        // out_b = gamma @ Wo (fp32)
        mgemm2<0><<<dim3(16, 8), 256, 0, stream>>>(
            g2h, g2l, WoTh, WoTl, 1024, out + (size_t)b * T_ * D_,
            nullptr, nullptr, nullptr, 1024);
    }
}